// Round 4
// baseline (11707.686 us; speedup 1.0000x reference)
//
#include <hip/hip_runtime.h>

typedef unsigned short u16;
typedef unsigned int u32;
typedef __attribute__((ext_vector_type(8))) short bf16x8;
typedef __attribute__((ext_vector_type(4))) float f32x4;

#define N_NODES 20000
#define N_EDGES 160000
#define DDIM    1000
#define KP      1024            // padded K / row stride (elements)

__device__ __forceinline__ float b2f(u16 u) {
    union { u32 i; float f; } v; v.i = ((u32)u) << 16; return v.f;
}
__device__ __forceinline__ u16 f2b(float f) {
    union { float f; u32 i; } v; v.f = f;
    u32 r = v.i + 0x7FFFu + ((v.i >> 16) & 1u);
    return (u16)(r >> 16);
}
__device__ __forceinline__ u32 pack2(float a, float b) {
    return (u32)f2b(a) | ((u32)f2b(b) << 16);
}
__device__ __forceinline__ f32x4 mfma16(bf16x8 a, bf16x8 b, f32x4 c) {
    return __builtin_amdgcn_mfma_f32_16x16x32_bf16(a, b, c, 0, 0, 0);
}
__device__ __forceinline__ float sigmoidf_(float x) { return 1.0f / (1.0f + expf(-x)); }

// async global->LDS DMA, 16 B per lane; lds dest = wave-uniform base + lane*16
__device__ __forceinline__ void gl2lds16(const u16* g, u16* l) {
    __builtin_amdgcn_global_load_lds(
        (const __attribute__((address_space(1))) u32*)g,
        (__attribute__((address_space(3))) u32*)l, 16, 0, 0);
}

// ---------------------------------------------------------------------------
// fp32 [rows][1000] -> bf16 [rows][1024], zero-padded cols. One block per row.
// ---------------------------------------------------------------------------
__global__ __launch_bounds__(256) void cvt_rows(const float* __restrict__ in,
                                                u16* __restrict__ out) {
    int r = blockIdx.x, c = threadIdx.x * 4;
    u32 o[2] = {0, 0};
    if (c < DDIM) {
        float4 v = *(const float4*)(in + (size_t)r * DDIM + c);
        o[0] = pack2(v.x, v.y); o[1] = pack2(v.z, v.w);
    }
    *(uint2*)(out + (size_t)r * KP + c) = *(const uint2*)o;
}

// ---------------------------------------------------------------------------
// weight[l] fp32 [k<1000][n<1000] -> Wt bf16 [n<1024][k<1024], zero-padded.
// ---------------------------------------------------------------------------
__global__ __launch_bounds__(256) void transpose_w(const float* __restrict__ W,
                                                   u16* __restrict__ Wt) {
    __shared__ u16 t[32][33];
    int l = blockIdx.z;
    int nb = blockIdx.x * 32, kb = blockIdx.y * 32;
    int x = threadIdx.x, y = threadIdx.y;   // block (32, 8)
    const float* Wl = W + (size_t)l * 1000000;
    u16* Wtl = Wt + (size_t)l * (KP * KP);
    for (int i = 0; i < 32; i += 8) {
        int k = kb + y + i, n = nb + x;
        t[y + i][x] = (k < DDIM && n < DDIM) ? f2b(Wl[(size_t)k * DDIM + n]) : (u16)0;
    }
    __syncthreads();
    for (int i = 0; i < 32; i += 8) {
        int n = nb + y + i, k = kb + x;
        Wtl[(size_t)n * KP + k] = t[x][y + i];   // n,k < 1024 by grid
    }
}

// ---------------------------------------------------------------------------
// CSR build (edge list constant): count -> scan -> fill
// ---------------------------------------------------------------------------
__global__ __launch_bounds__(256) void count_edges(const int* __restrict__ ei,
                                                   int* __restrict__ cnt) {
    int e = blockIdx.x * 256 + threadIdx.x;
    if (e < N_EDGES) atomicAdd(&cnt[ei[N_EDGES + e]], 1);
}

__global__ __launch_bounds__(1024) void scan_offsets(const int* __restrict__ cnt,
                                                     int* __restrict__ ofs) {
    __shared__ int s[1024];
    const int CH = 20;
    int t = threadIdx.x;
    int base = t * CH;
    int loc[CH];
    int sum = 0;
    for (int j = 0; j < CH; j++) {
        int i = base + j;
        loc[j] = sum;
        sum += (i < N_NODES) ? cnt[i] : 0;
    }
    s[t] = sum;
    __syncthreads();
    for (int d = 1; d < 1024; d <<= 1) {
        int v = (t >= d) ? s[t - d] : 0;
        __syncthreads();
        s[t] += v;
        __syncthreads();
    }
    int excl = s[t] - sum;
    for (int j = 0; j < CH; j++) {
        int i = base + j;
        if (i < N_NODES) ofs[i] = excl + loc[j];
    }
    if (t == 0) ofs[N_NODES] = N_EDGES;
}

__global__ __launch_bounds__(256) void fill_buckets(const int* __restrict__ ei,
                                                    const int* __restrict__ ofs,
                                                    int* __restrict__ cur,
                                                    int* __restrict__ bkt) {
    int e = blockIdx.x * 256 + threadIdx.x;
    if (e >= N_EDGES) return;
    int d = ei[N_EDGES + e];
    int pos = atomicAdd(&cur[d], 1);
    bkt[ofs[d] + pos] = e;
}

// ---------------------------------------------------------------------------
// agg[node] = sum_{e: dst=node} m[src(e)] * ew[e] — one block/node, no atomics
// ---------------------------------------------------------------------------
__global__ __launch_bounds__(256) void node_agg(const int* __restrict__ ei,
                                                const float* __restrict__ ew,
                                                const int* __restrict__ ofs,
                                                const int* __restrict__ bkt,
                                                const u16* __restrict__ m,
                                                u16* __restrict__ agg) {
    __shared__ int   s_src[64];
    __shared__ float s_w[64];
    int node = blockIdx.x;
    int t = threadIdx.x;                 // t<250 owns features [4t, 4t+4)
    int beg = ofs[node], end = ofs[node + 1];
    float4 acc = {0.f, 0.f, 0.f, 0.f};
    for (int cb = beg; cb < end; cb += 64) {
        int n = min(64, end - cb);
        if (t < n) {
            int e = bkt[cb + t];
            s_src[t] = ei[e];
            s_w[t]   = ew[e];
        }
        __syncthreads();
        if (t < 250) {
            for (int j = 0; j < n; j++) {
                int src = s_src[j];
                float w = s_w[j];
                uint2 v = *(const uint2*)(m + (size_t)src * KP + t * 4);
                const u16* p = (const u16*)&v;
                acc.x += b2f(p[0]) * w;
                acc.y += b2f(p[1]) * w;
                acc.z += b2f(p[2]) * w;
                acc.w += b2f(p[3]) * w;
            }
        }
        __syncthreads();
    }
    if (t < 250) {
        u32 o[2] = {pack2(acc.x, acc.y), pack2(acc.z, acc.w)};
        *(uint2*)(agg + (size_t)node * KP + t * 4) = *(const uint2*)o;
    }
}

// ---------------------------------------------------------------------------
// C[m<20000][n<1000] = A[m][k<1024] @ Bt[n][k<1024]^T  (all bf16, fp32 acc)
// m97 structure: 128x128 tile, BK=32, global_load_lds(16B), unpadded LDS.
// grid: 1256 blocks; bid&7 = n-tile (XCD locality), bid>>3 = m-tile.
// ---------------------------------------------------------------------------
__global__ __launch_bounds__(256) void gemm_bt(const u16* __restrict__ A,
                                               const u16* __restrict__ Bt,
                                               u16* __restrict__ C) {
    __shared__ u16 S[8192];              // Sa [128][32] @0, Sb [128][32] @4096
    int tid = threadIdx.x;
    int lane = tid & 63, wave = tid >> 6;
    int wr = wave >> 1, wc = wave & 1;
    int bid = blockIdx.x;
    int m0 = (bid >> 3) * 128, n0 = (bid & 7) * 128;

    const u16* pa[2]; const u16* pb[2];
    for (int i = 0; i < 2; i++) {
        int c = tid + 256 * i;           // chunk id 0..511
        int row = c >> 2, ch = c & 3;
        pa[i] = A  + (size_t)(m0 + row) * KP + ch * 8;
        pb[i] = Bt + (size_t)(n0 + row) * KP + ch * 8;
    }
    int su = wave * 512;                 // wave-uniform LDS chunk base (u16)
    f32x4 acc[4][4] = {};
    int fr = lane & 15, q = lane >> 4;

    for (int k0 = 0; k0 < KP; k0 += 32) {
        gl2lds16(pa[0], &S[su]);
        gl2lds16(pa[1], &S[su + 2048]);
        gl2lds16(pb[0], &S[4096 + su]);
        gl2lds16(pb[1], &S[4096 + su + 2048]);
        pa[0] += 32; pa[1] += 32; pb[0] += 32; pb[1] += 32;
        __syncthreads();
        bf16x8 af[4], bf[4];
        for (int i = 0; i < 4; i++)
            af[i] = *(const bf16x8*)&S[(wr * 64 + i * 16 + fr) * 32 + q * 8];
        for (int j = 0; j < 4; j++)
            bf[j] = *(const bf16x8*)&S[4096 + (wc * 64 + j * 16 + fr) * 32 + q * 8];
        for (int i = 0; i < 4; i++)
            for (int j = 0; j < 4; j++)
                acc[i][j] = mfma16(af[i], bf[j], acc[i][j]);
        __syncthreads();
    }

    int cc = lane & 15, r4 = q * 4;
    for (int i = 0; i < 4; i++)
        for (int j = 0; j < 4; j++) {
            int gn = n0 + wc * 64 + j * 16 + cc;
            if (gn >= DDIM) continue;
            for (int r = 0; r < 4; r++) {
                int gm = m0 + wr * 64 + i * 16 + r4 + r;
                if (gm < N_NODES) C[(size_t)gm * KP + gn] = f2b(acc[i][j][r]);
            }
        }
}

// ---------------------------------------------------------------------------
// Fused GRU: h_out = GRU(agg, h). 128 rows x 64 gate-cols per block.
// Per K-step: 10x global_load_lds (agg 2, h 2, 6 weight slabs), 192 MFMAs.
// grid 2512: xcd = bid&7 owns gate-col tiles {2*xcd, 2*xcd+1} (weights in L2).
// ---------------------------------------------------------------------------
__global__ __launch_bounds__(256, 2) void gru_fused(const u16* __restrict__ agg,
                                                    const u16* __restrict__ h,
                                                    const u16* __restrict__ wih,
                                                    const u16* __restrict__ whh,
                                                    const float* __restrict__ bih,
                                                    const float* __restrict__ bhh,
                                                    u16* __restrict__ hout) {
    __shared__ u16 S[20480];   // Sa[128][32]@0, Sh@4096, Sb[6][64][32]@8192
    int tid = threadIdx.x;
    int lane = tid & 63, wave = tid >> 6;
    int wr = wave >> 1, wc = wave & 1;

    int bid = blockIdx.x;
    int xcd = bid & 7;
    int s = bid >> 3;                     // 0..313
    int hi = (s >= 157) ? 1 : 0;
    int m0 = (s - hi * 157) * 128;
    int n0 = (xcd * 2 + hi) * 64;

    const u16* pa[2]; const u16* ph[2]; const u16* pb[6];
    for (int i = 0; i < 2; i++) {
        int c = tid + 256 * i;            // 0..511
        int row = c >> 2, ch = c & 3;
        pa[i] = agg + (size_t)(m0 + row) * KP + ch * 8;
        ph[i] = h   + (size_t)(m0 + row) * KP + ch * 8;
    }
    for (int g = 0; g < 6; g++) {
        int c = tid + 256 * g;            // slab = g, row = (c>>2)&63
        int row = (c >> 2) & 63, ch = c & 3;
        const u16* base = (g < 3) ? wih : whh;
        int grow = ((g < 3) ? g : g - 3) * 1000 + n0 + row;
        pb[g] = base + (size_t)grow * KP + ch * 8;
    }
    int su = wave * 512;

    f32x4 ar[4][2] = {}, az[4][2] = {}, ain[4][2] = {}, ahn[4][2] = {};
    int fr = lane & 15, q = lane >> 4;

    for (int k0 = 0; k0 < KP; k0 += 32) {
        gl2lds16(pa[0], &S[su]);
        gl2lds16(pa[1], &S[su + 2048]);
        gl2lds16(ph[0], &S[4096 + su]);
        gl2lds16(ph[1], &S[4096 + su + 2048]);
        for (int g = 0; g < 6; g++)
            gl2lds16(pb[g], &S[8192 + g * 2048 + su]);
        pa[0] += 32; pa[1] += 32; ph[0] += 32; ph[1] += 32;
        for (int g = 0; g < 6; g++) pb[g] += 32;
        __syncthreads();

        bf16x8 aa[4], ah[4], bx[2], by[2];
        for (int i = 0; i < 4; i++) {
            int off = (wr * 64 + i * 16 + fr) * 32 + q * 8;
            aa[i] = *(const bf16x8*)&S[off];
            ah[i] = *(const bf16x8*)&S[4096 + off];
        }
        int boff0 = (wc * 32 + fr) * 32 + q * 8;
        int boff1 = boff0 + 16 * 32;
        // r-gate: slabs 0 (ih_r) + 3 (hh_r)
        bx[0] = *(const bf16x8*)&S[8192 + boff0];
        bx[1] = *(const bf16x8*)&S[8192 + boff1];
        by[0] = *(const bf16x8*)&S[8192 + 3 * 2048 + boff0];
        by[1] = *(const bf16x8*)&S[8192 + 3 * 2048 + boff1];
        for (int i = 0; i < 4; i++)
            for (int j = 0; j < 2; j++) {
                ar[i][j] = mfma16(aa[i], bx[j], ar[i][j]);
                ar[i][j] = mfma16(ah[i], by[j], ar[i][j]);
            }
        // z-gate: slabs 1 + 4
        bx[0] = *(const bf16x8*)&S[8192 + 1 * 2048 + boff0];
        bx[1] = *(const bf16x8*)&S[8192 + 1 * 2048 + boff1];
        by[0] = *(const bf16x8*)&S[8192 + 4 * 2048 + boff0];
        by[1] = *(const bf16x8*)&S[8192 + 4 * 2048 + boff1];
        for (int i = 0; i < 4; i++)
            for (int j = 0; j < 2; j++) {
                az[i][j] = mfma16(aa[i], bx[j], az[i][j]);
                az[i][j] = mfma16(ah[i], by[j], az[i][j]);
            }
        // n-gate inputs: slab 2 (agg side), slab 5 (h side)
        bx[0] = *(const bf16x8*)&S[8192 + 2 * 2048 + boff0];
        bx[1] = *(const bf16x8*)&S[8192 + 2 * 2048 + boff1];
        by[0] = *(const bf16x8*)&S[8192 + 5 * 2048 + boff0];
        by[1] = *(const bf16x8*)&S[8192 + 5 * 2048 + boff1];
        for (int i = 0; i < 4; i++)
            for (int j = 0; j < 2; j++) {
                ain[i][j] = mfma16(aa[i], bx[j], ain[i][j]);
                ahn[i][j] = mfma16(ah[i], by[j], ahn[i][j]);
            }
        __syncthreads();
    }

    int cc = lane & 15, r4 = q * 4;
    for (int j = 0; j < 2; j++) {
        int gn = n0 + wc * 32 + j * 16 + cc;
        if (gn >= DDIM) continue;
        float br  = bih[gn] + bhh[gn];
        float bz  = bih[1000 + gn] + bhh[1000 + gn];
        float bni = bih[2000 + gn];
        float bnh = bhh[2000 + gn];
        for (int i = 0; i < 4; i++)
            for (int r = 0; r < 4; r++) {
                int gm = m0 + wr * 64 + i * 16 + r4 + r;
                if (gm >= N_NODES) continue;
                float rg = sigmoidf_(ar[i][j][r] + br);
                float zg = sigmoidf_(az[i][j][r] + bz);
                float ng = tanhf(ain[i][j][r] + bni + rg * (ahn[i][j][r] + bnh));
                size_t idx = (size_t)gm * KP + gn;
                float hp = b2f(h[idx]);
                hout[idx] = f2b((1.0f - zg) * ng + zg * hp);
            }
    }
}

// ---------------------------------------------------------------------------
// out[row] (fp32) = relu(h[row]) . fc_w + fc_b — one wave per row
// ---------------------------------------------------------------------------
__global__ __launch_bounds__(256) void fc_out(const u16* __restrict__ h,
                                              const float* __restrict__ fw,
                                              const float* __restrict__ fb,
                                              float* __restrict__ out) {
    int row = blockIdx.x * 4 + (threadIdx.x >> 6);
    int lane = threadIdx.x & 63;
    if (row >= N_NODES) return;
    float s = 0.0f;
    for (int i = 0; i < 4; i++) {
        int c = lane + 64 * i;
        if (c < 250) {
            uint2 v = *(const uint2*)(h + (size_t)row * KP + c * 4);
            float4 w = *(const float4*)(fw + c * 4);
            const u16* pv = (const u16*)&v;
            float h0 = b2f(pv[0]), h1 = b2f(pv[1]), h2 = b2f(pv[2]), h3 = b2f(pv[3]);
            s += (h0 > 0.0f ? h0 : 0.0f) * w.x;
            s += (h1 > 0.0f ? h1 : 0.0f) * w.y;
            s += (h2 > 0.0f ? h2 : 0.0f) * w.z;
            s += (h3 > 0.0f ? h3 : 0.0f) * w.w;
        }
    }
    for (int off = 32; off > 0; off >>= 1) s += __shfl_down(s, off, 64);
    if (lane == 0) out[row] = s + fb[0];
}

// ---------------------------------------------------------------------------
extern "C" void kernel_launch(void* const* d_in, const int* in_sizes, int n_in,
                              void* d_out, int out_size, void* d_ws, size_t ws_size,
                              hipStream_t stream) {
    const float* x   = (const float*)d_in[0];
    const int*   ei  = (const int*)d_in[1];
    const float* ew  = (const float*)d_in[2];
    const float* W   = (const float*)d_in[3];
    const float* wih = (const float*)d_in[4];
    const float* whh = (const float*)d_in[5];
    const float* bih = (const float*)d_in[6];
    const float* bhh = (const float*)d_in[7];
    const float* fw  = (const float*)d_in[8];
    const float* fb  = (const float*)d_in[9];
    float* out = (float*)d_out;

    // workspace (~144 MB; harness provides >=178 MB per earlier rounds)
    char* ws = (char*)d_ws;
    u16* xb    = (u16*)(ws);                   // 41 MB [20000][1024] bf16
    u16* bufA  = (u16*)(ws +  41000000);       // 41 MB
    u16* bufB  = (u16*)(ws +  82000000);       // 41 MB (agg)
    u16* Wt    = (u16*)(ws + 123000000);       // 6.3 MB [3][1024][1024]
    u16* wih_b = (u16*)(ws + 129400000);       // 6.3 MB [3072][1024] (3000 real)
    u16* whh_b = (u16*)(ws + 135800000);       // 6.3 MB
    int* cnt   = (int*)(ws + 143000000);       // 80 KB
    int* cur   = (int*)(ws + 143100000);       // 80 KB
    int* ofs   = (int*)(ws + 143200000);       // 80 KB + 4
    int* bkt   = (int*)(ws + 143300096);       // 640 KB

    // one-time conversions + CSR build
    cvt_rows<<<N_NODES, 256, 0, stream>>>(x, xb);
    cvt_rows<<<3000, 256, 0, stream>>>(wih, wih_b);
    cvt_rows<<<3000, 256, 0, stream>>>(whh, whh_b);
    transpose_w<<<dim3(32, 32, 3), dim3(32, 8), 0, stream>>>(W, Wt);
    hipMemsetAsync(cnt, 0, 160000, stream);    // covers cnt + gap; cur below
    hipMemsetAsync(cur, 0, 80000, stream);
    count_edges<<<625, 256, 0, stream>>>(ei, cnt);
    scan_offsets<<<1, 1024, 0, stream>>>(cnt, ofs);
    fill_buckets<<<625, 256, 0, stream>>>(ei, ofs, cur, bkt);

    // layer 0: h = xb; m -> bufA; agg -> bufB; h1 -> bufA (m dead)
    gemm_bt<<<1256, 256, 0, stream>>>(xb, Wt, bufA);
    node_agg<<<N_NODES, 256, 0, stream>>>(ei, ew, ofs, bkt, bufA, bufB);
    gru_fused<<<2512, 256, 0, stream>>>(bufB, xb, wih_b, whh_b, bih, bhh, bufA);

    // layer 1: h = bufA; m -> xb (x dead); agg -> bufB; h2 -> xb
    gemm_bt<<<1256, 256, 0, stream>>>(bufA, Wt + 1048576, xb);
    node_agg<<<N_NODES, 256, 0, stream>>>(ei, ew, ofs, bkt, xb, bufB);
    gru_fused<<<2512, 256, 0, stream>>>(bufB, bufA, wih_b, whh_b, bih, bhh, xb);

    // layer 2: h = xb; m -> bufA; agg -> bufB; h3 -> bufA
    gemm_bt<<<1256, 256, 0, stream>>>(xb, Wt + 2097152, bufA);
    node_agg<<<N_NODES, 256, 0, stream>>>(ei, ew, ofs, bkt, bufA, bufB);
    gru_fused<<<2512, 256, 0, stream>>>(bufB, xb, wih_b, whh_b, bih, bhh, bufA);

    // out = relu(h3) @ fc_w^T + fc_b
    fc_out<<<5000, 256, 0, stream>>>(bufA, fw, fb, out);
}

// Round 5
// 1801.498 us; speedup vs baseline: 6.4989x; 6.4989x over previous
//
#include <hip/hip_runtime.h>

typedef unsigned short u16;
typedef unsigned int u32;
typedef __attribute__((ext_vector_type(8))) short bf16x8;
typedef __attribute__((ext_vector_type(4))) float f32x4;

#define N_NODES 20000
#define N_EDGES 160000
#define DDIM    1000
#define KP      1024            // padded K / row stride (elements)

__device__ __forceinline__ float b2f(u16 u) {
    union { u32 i; float f; } v; v.i = ((u32)u) << 16; return v.f;
}
__device__ __forceinline__ u16 f2b(float f) {
    union { float f; u32 i; } v; v.f = f;
    u32 r = v.i + 0x7FFFu + ((v.i >> 16) & 1u);
    return (u16)(r >> 16);
}
__device__ __forceinline__ u32 pack2(float a, float b) {
    return (u32)f2b(a) | ((u32)f2b(b) << 16);
}
__device__ __forceinline__ f32x4 mfma16(bf16x8 a, bf16x8 b, f32x4 c) {
    return __builtin_amdgcn_mfma_f32_16x16x32_bf16(a, b, c, 0, 0, 0);
}
__device__ __forceinline__ float sigmoidf_(float x) { return 1.0f / (1.0f + expf(-x)); }

// async global->LDS DMA, 16 B per lane; lds dest = wave-uniform base + lane*16
__device__ __forceinline__ void gl2lds16(const u16* g, u16* l) {
    __builtin_amdgcn_global_load_lds(
        (const __attribute__((address_space(1))) u32*)g,
        (__attribute__((address_space(3))) u32*)l, 16, 0, 0);
}

// ---------------------------------------------------------------------------
// fp32 [rows][1000] -> bf16 [rows][1024], zero-padded cols. One block per row.
// ---------------------------------------------------------------------------
__global__ __launch_bounds__(256) void cvt_rows(const float* __restrict__ in,
                                                u16* __restrict__ out) {
    int r = blockIdx.x, c = threadIdx.x * 4;
    u32 o[2] = {0, 0};
    if (c < DDIM) {
        float4 v = *(const float4*)(in + (size_t)r * DDIM + c);
        o[0] = pack2(v.x, v.y); o[1] = pack2(v.z, v.w);
    }
    *(uint2*)(out + (size_t)r * KP + c) = *(const uint2*)o;
}

// ---------------------------------------------------------------------------
// GRU weight repack: in fp32 [3000][1000] -> out bf16 slabs [3][1024][1024]
// (slab s rows [0,1000) = in rows [s*1000, s*1000+1000); pad pre-zeroed)
// ---------------------------------------------------------------------------
__global__ __launch_bounds__(256) void cvt_rows_slab(const float* __restrict__ in,
                                                     u16* __restrict__ out) {
    int r = blockIdx.x;                 // 0..2999
    int slab = r / 1000, rr = r - slab * 1000;
    int c = threadIdx.x * 4;
    u32 o[2] = {0, 0};
    if (c < DDIM) {
        float4 v = *(const float4*)(in + (size_t)r * DDIM + c);
        o[0] = pack2(v.x, v.y); o[1] = pack2(v.z, v.w);
    }
    *(uint2*)(out + ((size_t)slab * KP + rr) * KP + c) = *(const uint2*)o;
}

// ---------------------------------------------------------------------------
// weight[l] fp32 [k<1000][n<1000] -> Wt bf16 [n<1024][k<1024], zero-padded.
// ---------------------------------------------------------------------------
__global__ __launch_bounds__(256) void transpose_w(const float* __restrict__ W,
                                                   u16* __restrict__ Wt) {
    __shared__ u16 t[32][33];
    int l = blockIdx.z;
    int nb = blockIdx.x * 32, kb = blockIdx.y * 32;
    int x = threadIdx.x, y = threadIdx.y;   // block (32, 8)
    const float* Wl = W + (size_t)l * 1000000;
    u16* Wtl = Wt + (size_t)l * (KP * KP);
    for (int i = 0; i < 32; i += 8) {
        int k = kb + y + i, n = nb + x;
        t[y + i][x] = (k < DDIM && n < DDIM) ? f2b(Wl[(size_t)k * DDIM + n]) : (u16)0;
    }
    __syncthreads();
    for (int i = 0; i < 32; i += 8) {
        int n = nb + y + i, k = kb + x;
        Wtl[(size_t)n * KP + k] = t[x][y + i];   // n,k < 1024 by grid
    }
}

// ---------------------------------------------------------------------------
// CSR build (edge list constant): count -> scan -> fill
// ---------------------------------------------------------------------------
__global__ __launch_bounds__(256) void count_edges(const int* __restrict__ ei,
                                                   int* __restrict__ cnt) {
    int e = blockIdx.x * 256 + threadIdx.x;
    if (e < N_EDGES) atomicAdd(&cnt[ei[N_EDGES + e]], 1);
}

__global__ __launch_bounds__(1024) void scan_offsets(const int* __restrict__ cnt,
                                                     int* __restrict__ ofs) {
    __shared__ int s[1024];
    const int CH = 20;
    int t = threadIdx.x;
    int base = t * CH;
    int loc[CH];
    int sum = 0;
    for (int j = 0; j < CH; j++) {
        int i = base + j;
        loc[j] = sum;
        sum += (i < N_NODES) ? cnt[i] : 0;
    }
    s[t] = sum;
    __syncthreads();
    for (int d = 1; d < 1024; d <<= 1) {
        int v = (t >= d) ? s[t - d] : 0;
        __syncthreads();
        s[t] += v;
        __syncthreads();
    }
    int excl = s[t] - sum;
    for (int j = 0; j < CH; j++) {
        int i = base + j;
        if (i < N_NODES) ofs[i] = excl + loc[j];
    }
    if (t == 0) ofs[N_NODES] = N_EDGES;
}

__global__ __launch_bounds__(256) void fill_buckets(const int* __restrict__ ei,
                                                    const int* __restrict__ ofs,
                                                    int* __restrict__ cur,
                                                    int* __restrict__ bkt) {
    int e = blockIdx.x * 256 + threadIdx.x;
    if (e >= N_EDGES) return;
    int d = ei[N_EDGES + e];
    int pos = atomicAdd(&cur[d], 1);
    bkt[ofs[d] + pos] = e;
}

// ---------------------------------------------------------------------------
// agg[node] = sum_{e: dst=node} m[src(e)] * ew[e] — one block/node, no atomics
// ---------------------------------------------------------------------------
__global__ __launch_bounds__(256) void node_agg(const int* __restrict__ ei,
                                                const float* __restrict__ ew,
                                                const int* __restrict__ ofs,
                                                const int* __restrict__ bkt,
                                                const u16* __restrict__ m,
                                                u16* __restrict__ agg) {
    __shared__ int   s_src[64];
    __shared__ float s_w[64];
    int node = blockIdx.x;
    int t = threadIdx.x;                 // t<250 owns features [4t, 4t+4)
    int beg = ofs[node], end = ofs[node + 1];
    float4 acc = {0.f, 0.f, 0.f, 0.f};
    for (int cb = beg; cb < end; cb += 64) {
        int n = min(64, end - cb);
        if (t < n) {
            int e = bkt[cb + t];
            s_src[t] = ei[e];
            s_w[t]   = ew[e];
        }
        __syncthreads();
        if (t < 250) {
            for (int j = 0; j < n; j++) {
                int src = s_src[j];
                float w = s_w[j];
                uint2 v = *(const uint2*)(m + (size_t)src * KP + t * 4);
                const u16* p = (const u16*)&v;
                acc.x += b2f(p[0]) * w;
                acc.y += b2f(p[1]) * w;
                acc.z += b2f(p[2]) * w;
                acc.w += b2f(p[3]) * w;
            }
        }
        __syncthreads();
    }
    if (t < 250) {
        u32 o[2] = {pack2(acc.x, acc.y), pack2(acc.z, acc.w)};
        *(uint2*)(agg + (size_t)node * KP + t * 4) = *(const uint2*)o;
    }
}

// ---------------------------------------------------------------------------
// C[m<20000][n<1000] = A[m][k<1024] @ Bt[n][k<1024]^T  (all bf16, fp32 acc)
// m97 structure: 128x128 tile, BK=32, global_load_lds(16B), unpadded LDS.
// ---------------------------------------------------------------------------
__global__ __launch_bounds__(256) void gemm_bt(const u16* __restrict__ A,
                                               const u16* __restrict__ Bt,
                                               u16* __restrict__ C) {
    __shared__ u16 S[8192];              // Sa [128][32] @0, Sb [128][32] @4096
    int tid = threadIdx.x;
    int lane = tid & 63, wave = tid >> 6;
    int wr = wave >> 1, wc = wave & 1;
    int bid = blockIdx.x;
    int m0 = (bid >> 3) * 128, n0 = (bid & 7) * 128;

    const u16* pa0 = A  + (size_t)(m0 + (tid >> 2)) * KP + (tid & 3) * 8;
    const u16* pa1 = pa0 + (size_t)64 * KP;
    const u16* pb0 = Bt + (size_t)(n0 + (tid >> 2)) * KP + (tid & 3) * 8;
    const u16* pb1 = pb0 + (size_t)64 * KP;
    int su = wave * 512;                 // wave-uniform LDS chunk base (u16)
    f32x4 acc[4][4] = {};
    int fr = lane & 15, q = lane >> 4;

    for (int k0 = 0; k0 < KP; k0 += 32) {
        gl2lds16(pa0, &S[su]);
        gl2lds16(pa1, &S[su + 2048]);
        gl2lds16(pb0, &S[4096 + su]);
        gl2lds16(pb1, &S[4096 + su + 2048]);
        pa0 += 32; pa1 += 32; pb0 += 32; pb1 += 32;
        __syncthreads();
        bf16x8 af[4], bf[4];
#pragma unroll
        for (int i = 0; i < 4; i++)
            af[i] = *(const bf16x8*)&S[(wr * 64 + i * 16 + fr) * 32 + q * 8];
#pragma unroll
        for (int j = 0; j < 4; j++)
            bf[j] = *(const bf16x8*)&S[4096 + (wc * 64 + j * 16 + fr) * 32 + q * 8];
#pragma unroll
        for (int i = 0; i < 4; i++)
#pragma unroll
            for (int j = 0; j < 4; j++)
                acc[i][j] = mfma16(af[i], bf[j], acc[i][j]);
        __syncthreads();
    }

    int cc = lane & 15, r4 = q * 4;
#pragma unroll
    for (int i = 0; i < 4; i++)
#pragma unroll
        for (int j = 0; j < 4; j++) {
            int gn = n0 + wc * 64 + j * 16 + cc;
            if (gn >= DDIM) continue;
#pragma unroll
            for (int r = 0; r < 4; r++) {
                int gm = m0 + wr * 64 + i * 16 + r4 + r;
                if (gm < N_NODES) C[(size_t)gm * KP + gn] = f2b(acc[i][j][r]);
            }
        }
}

// ---------------------------------------------------------------------------
// Fused GRU: h_out = GRU(agg, h). 128 rows x 64 gate-cols per block.
// wb = [6][1024][1024] bf16 slabs: 0..2 = w_ih r,z,n ; 3..5 = w_hh r,z,n.
// Single acc array (gate-major, constant-indexed) to keep it in registers.
// ---------------------------------------------------------------------------
__global__ __launch_bounds__(256) void gru_fused(const u16* __restrict__ agg,
                                                 const u16* __restrict__ h,
                                                 const u16* __restrict__ wb,
                                                 const float* __restrict__ bih,
                                                 const float* __restrict__ bhh,
                                                 u16* __restrict__ hout) {
    __shared__ u16 S[20480];   // Sa[128][32]@0, Sh@4096, W[g][64][32]@8192+g*2048
    int tid = threadIdx.x;
    int lane = tid & 63, wave = tid >> 6;
    int wr = wave >> 1, wc = wave & 1;

    int bid = blockIdx.x;
    int xcd = bid & 7;
    int s = bid >> 3;                     // 0..313
    int hi = (s >= 157) ? 1 : 0;
    int m0 = (s - hi * 157) * 128;
    int n0 = (xcd * 2 + hi) * 64;

    const u16* pa0 = agg + (size_t)(m0 + (tid >> 2)) * KP + (tid & 3) * 8;
    const u16* pa1 = pa0 + (size_t)64 * KP;
    const u16* ph0 = h   + (size_t)(m0 + (tid >> 2)) * KP + (tid & 3) * 8;
    const u16* ph1 = ph0 + (size_t)64 * KP;
    const u16* pw  = wb  + (size_t)(n0 + (tid >> 2)) * KP + (tid & 3) * 8;
    int su = wave * 512;

    // acc[gate][i][j]: gate 0=r, 1=z, 2=i_n, 3=h_n
    f32x4 acc[4][4][2] = {};
    int fr = lane & 15, q = lane >> 4;

    for (int k0 = 0; k0 < KP; k0 += 32) {
        gl2lds16(pa0, &S[su]);
        gl2lds16(pa1, &S[su + 2048]);
        gl2lds16(ph0, &S[4096 + su]);
        gl2lds16(ph1, &S[4096 + su + 2048]);
#pragma unroll
        for (int g = 0; g < 6; g++)
            gl2lds16(pw + (size_t)g * (KP * KP), &S[8192 + g * 2048 + su]);
        pa0 += 32; pa1 += 32; ph0 += 32; ph1 += 32; pw += 32;
        __syncthreads();

        bf16x8 aa[4], ah[4];
#pragma unroll
        for (int i = 0; i < 4; i++) {
            int off = (wr * 64 + i * 16 + fr) * 32 + q * 8;
            aa[i] = *(const bf16x8*)&S[off];
            ah[i] = *(const bf16x8*)&S[4096 + off];
        }
        int boff0 = (wc * 32 + fr) * 32 + q * 8;
        int boff1 = boff0 + 512;          // +16 rows
        bf16x8 bx[2], by[2];
        // r-gate: slab 0 (ih) with agg, slab 3 (hh) with h
        bx[0] = *(const bf16x8*)&S[8192 + boff0];
        bx[1] = *(const bf16x8*)&S[8192 + boff1];
        by[0] = *(const bf16x8*)&S[8192 + 3 * 2048 + boff0];
        by[1] = *(const bf16x8*)&S[8192 + 3 * 2048 + boff1];
#pragma unroll
        for (int i = 0; i < 4; i++)
#pragma unroll
            for (int j = 0; j < 2; j++) {
                acc[0][i][j] = mfma16(aa[i], bx[j], acc[0][i][j]);
                acc[0][i][j] = mfma16(ah[i], by[j], acc[0][i][j]);
            }
        // z-gate: slabs 1 + 4
        bx[0] = *(const bf16x8*)&S[8192 + 1 * 2048 + boff0];
        bx[1] = *(const bf16x8*)&S[8192 + 1 * 2048 + boff1];
        by[0] = *(const bf16x8*)&S[8192 + 4 * 2048 + boff0];
        by[1] = *(const bf16x8*)&S[8192 + 4 * 2048 + boff1];
#pragma unroll
        for (int i = 0; i < 4; i++)
#pragma unroll
            for (int j = 0; j < 2; j++) {
                acc[1][i][j] = mfma16(aa[i], bx[j], acc[1][i][j]);
                acc[1][i][j] = mfma16(ah[i], by[j], acc[1][i][j]);
            }
        // n-gate: slab 2 (ih, agg side), slab 5 (hh, h side)
        bx[0] = *(const bf16x8*)&S[8192 + 2 * 2048 + boff0];
        bx[1] = *(const bf16x8*)&S[8192 + 2 * 2048 + boff1];
        by[0] = *(const bf16x8*)&S[8192 + 5 * 2048 + boff0];
        by[1] = *(const bf16x8*)&S[8192 + 5 * 2048 + boff1];
#pragma unroll
        for (int i = 0; i < 4; i++)
#pragma unroll
            for (int j = 0; j < 2; j++) {
                acc[2][i][j] = mfma16(aa[i], bx[j], acc[2][i][j]);
                acc[3][i][j] = mfma16(ah[i], by[j], acc[3][i][j]);
            }
        __syncthreads();
    }

    int cc = lane & 15, r4 = q * 4;
#pragma unroll
    for (int j = 0; j < 2; j++) {
        int gn = n0 + wc * 32 + j * 16 + cc;
        if (gn >= DDIM) continue;
        float br  = bih[gn] + bhh[gn];
        float bz  = bih[1000 + gn] + bhh[1000 + gn];
        float bni = bih[2000 + gn];
        float bnh = bhh[2000 + gn];
#pragma unroll
        for (int i = 0; i < 4; i++)
#pragma unroll
            for (int r = 0; r < 4; r++) {
                int gm = m0 + wr * 64 + i * 16 + r4 + r;
                if (gm >= N_NODES) continue;
                float rg = sigmoidf_(acc[0][i][j][r] + br);
                float zg = sigmoidf_(acc[1][i][j][r] + bz);
                float ng = tanhf(acc[2][i][j][r] + bni + rg * (acc[3][i][j][r] + bnh));
                size_t idx = (size_t)gm * KP + gn;
                float hp = b2f(h[idx]);
                hout[idx] = f2b((1.0f - zg) * ng + zg * hp);
            }
    }
}

// ---------------------------------------------------------------------------
// out[row] (fp32) = relu(h[row]) . fc_w + fc_b — one wave per row
// ---------------------------------------------------------------------------
__global__ __launch_bounds__(256) void fc_out(const u16* __restrict__ h,
                                              const float* __restrict__ fw,
                                              const float* __restrict__ fb,
                                              float* __restrict__ out) {
    int row = blockIdx.x * 4 + (threadIdx.x >> 6);
    int lane = threadIdx.x & 63;
    if (row >= N_NODES) return;
    float s = 0.0f;
    for (int i = 0; i < 4; i++) {
        int c = lane + 64 * i;
        if (c < 250) {
            uint2 v = *(const uint2*)(h + (size_t)row * KP + c * 4);
            float4 w = *(const float4*)(fw + c * 4);
            const u16* pv = (const u16*)&v;
            float h0 = b2f(pv[0]), h1 = b2f(pv[1]), h2 = b2f(pv[2]), h3 = b2f(pv[3]);
            s += (h0 > 0.0f ? h0 : 0.0f) * w.x;
            s += (h1 > 0.0f ? h1 : 0.0f) * w.y;
            s += (h2 > 0.0f ? h2 : 0.0f) * w.z;
            s += (h3 > 0.0f ? h3 : 0.0f) * w.w;
        }
    }
    for (int off = 32; off > 0; off >>= 1) s += __shfl_down(s, off, 64);
    if (lane == 0) out[row] = s + fb[0];
}

// ---------------------------------------------------------------------------
extern "C" void kernel_launch(void* const* d_in, const int* in_sizes, int n_in,
                              void* d_out, int out_size, void* d_ws, size_t ws_size,
                              hipStream_t stream) {
    const float* x   = (const float*)d_in[0];
    const int*   ei  = (const int*)d_in[1];
    const float* ew  = (const float*)d_in[2];
    const float* W   = (const float*)d_in[3];
    const float* wih = (const float*)d_in[4];
    const float* whh = (const float*)d_in[5];
    const float* bih = (const float*)d_in[6];
    const float* bhh = (const float*)d_in[7];
    const float* fw  = (const float*)d_in[8];
    const float* fb  = (const float*)d_in[9];
    float* out = (float*)d_out;

    // workspace (~143 MB)
    char* ws = (char*)d_ws;
    u16* xb   = (u16*)(ws);                   // 41 MB [20000][1024] bf16
    u16* bufA = (u16*)(ws +  41000000);       // 41 MB
    u16* bufB = (u16*)(ws +  82000000);       // 41 MB (agg)
    u16* Wt   = (u16*)(ws + 123000000);       // 6.3 MB [3][1024][1024]
    u16* wb   = (u16*)(ws + 129500000);       // 12.6 MB [6][1024][1024]
    int* cnt  = (int*)(ws + 142200000);       // 80 KB
    int* cur  = (int*)(ws + 142300000);       // 80 KB
    int* ofs  = (int*)(ws + 142400000);       // 80 KB + 4
    int* bkt  = (int*)(ws + 142500096);       // 640 KB

    // one-time conversions + CSR build
    cvt_rows<<<N_NODES, 256, 0, stream>>>(x, xb);
    hipMemsetAsync(wb, 0, (size_t)6 * KP * KP * 2, stream);
    cvt_rows_slab<<<3000, 256, 0, stream>>>(wih, wb);
    cvt_rows_slab<<<3000, 256, 0, stream>>>(whh, wb + (size_t)3 * KP * KP);
    transpose_w<<<dim3(32, 32, 3), dim3(32, 8), 0, stream>>>(W, Wt);
    hipMemsetAsync(cnt, 0, 80000, stream);
    hipMemsetAsync(cur, 0, 80000, stream);
    count_edges<<<625, 256, 0, stream>>>(ei, cnt);
    scan_offsets<<<1, 1024, 0, stream>>>(cnt, ofs);
    fill_buckets<<<625, 256, 0, stream>>>(ei, ofs, cur, bkt);

    // layer 0: h = xb; m -> bufA; agg -> bufB; h1 -> bufA (m dead)
    gemm_bt<<<1256, 256, 0, stream>>>(xb, Wt, bufA);
    node_agg<<<N_NODES, 256, 0, stream>>>(ei, ew, ofs, bkt, bufA, bufB);
    gru_fused<<<2512, 256, 0, stream>>>(bufB, xb, wb, bih, bhh, bufA);

    // layer 1: h = bufA; m -> xb (x dead); agg -> bufB; h2 -> xb
    gemm_bt<<<1256, 256, 0, stream>>>(bufA, Wt + 1048576, xb);
    node_agg<<<N_NODES, 256, 0, stream>>>(ei, ew, ofs, bkt, xb, bufB);
    gru_fused<<<2512, 256, 0, stream>>>(bufB, bufA, wb, bih, bhh, xb);

    // layer 2: h = xb; m -> bufA; agg -> bufB; h3 -> bufA
    gemm_bt<<<1256, 256, 0, stream>>>(xb, Wt + 2097152, bufA);
    node_agg<<<N_NODES, 256, 0, stream>>>(ei, ew, ofs, bkt, bufA, bufB);
    gru_fused<<<2512, 256, 0, stream>>>(bufB, xb, wb, bih, bhh, bufA);

    // out = relu(h3) @ fc_w^T + fc_b
    fc_out<<<5000, 256, 0, stream>>>(bufA, fw, fb, out);
}